// Round 1
// baseline (41.202 us; speedup 1.0000x reference)
//
#include <hip/hip_runtime.h>

// Problem constants (from reference): B=2, C=8, H=256, W=512 -> out [B,C,25,H,W] f32
#define BH 256
#define BW 512
#define BCN 16          // B*C
#define HWSZ (BH * BW)  // 131072

__global__ __launch_bounds__(256) void eprod25_kernel(
    const float* __restrict__ e, const float* __restrict__ ce,
    float* __restrict__ out)
{
    const int x  = blockIdx.x * 64 + (threadIdx.x & 63);
    const int y  = blockIdx.y * 4  + (threadIdx.x >> 6);
    const int bc = blockIdx.z;

    const float* __restrict__ ebase = e  + (size_t)bc * HWSZ;
    const float* __restrict__ cbase = ce + (size_t)bc * HWSZ;

    // 5x5 zero-padded register patches centered at (y, x)
    float ev[5][5], cv[5][5];
#pragma unroll
    for (int di = 0; di < 5; ++di) {
        const int iy = y - 2 + di;
        const bool rok = (unsigned)iy < (unsigned)BH;
#pragma unroll
        for (int dj = 0; dj < 5; ++dj) {
            const int ix = x - 2 + dj;
            const bool ok = rok && ((unsigned)ix < (unsigned)BW);
            const size_t idx = (size_t)iy * BW + ix;
            ev[di][dj] = ok ? ebase[idx] : 0.f;
            cv[di][dj] = ok ? cbase[idx] : 0.f;
        }
    }

    // E(k) = ev[1+k/3][1+k%3]; E(4) = 1 (ones channel)
    const float E0 = ev[1][1], E1 = ev[1][2], E2 = ev[1][3];
    const float E3 = ev[2][1],               E5 = ev[2][3];
    const float E6 = ev[3][1], E7 = ev[3][2], E8 = ev[3][3];
    const float C0 = cv[1][1], C1 = cv[1][2], C2 = cv[1][3];
    const float C3 = cv[2][1],               C5 = cv[2][3];
    const float C6 = cv[3][1], C7 = cv[3][2], C8 = cv[3][3];

    // Intermediate-pad validity masks for Ep(k, r, c): (y+r-1, x+c-1) in bounds
    const bool rok0 = (y >= 1), rok2 = (y <= BH - 2);
    const bool cok0 = (x >= 1), cok2 = (x <= BW - 2);
    const bool m00 = rok0 && cok0, m01 = rok0, m02 = rok0 && cok2;
    const bool m10 = cok0,                     m12 = cok2;
    const bool m20 = rok2 && cok0, m21 = rok2, m22 = rok2 && cok2;

#define MV(arr, di, dj, m) ((m) ? arr[di][dj] : 0.f)

    // first-occurrence argmax semantics (strict >)
    auto sel2 = [](float a0, float a1, float c0, float c1) {
        return (c1 > c0) ? a1 : a0;
    };
    auto sel3 = [](float a0, float a1, float a2, float c0, float c1, float c2) {
        float best = c0, a = a0;
        if (c1 > best) { best = c1; a = a1; }
        if (c2 > best) { a = a2; }
        return a;
    };

    // Corners
    const float e00 = E0 * MV(ev, 0, 0, m00);
    const float e04 = E2 * MV(ev, 0, 4, m02);
    const float e40 = E6 * MV(ev, 4, 0, m20);
    const float e44 = E8 * MV(ev, 4, 4, m22);

    // Left column
    const float e10 = sel2(E0 * MV(ev, 1, 0, m00), E3 * MV(ev, 1, 0, m10),
                           C0 * MV(cv, 1, 0, m00), C3 * MV(cv, 1, 0, m10));
    const float e20 = sel3(E0 * MV(ev, 2, 0, m00), E3 * MV(ev, 2, 0, m10), E6 * MV(ev, 2, 0, m20),
                           C0 * MV(cv, 2, 0, m00), C3 * MV(cv, 2, 0, m10), C6 * MV(cv, 2, 0, m20));
    const float e30 = sel2(E3 * MV(ev, 3, 0, m10), E6 * MV(ev, 3, 0, m20),
                           C3 * MV(cv, 3, 0, m10), C6 * MV(cv, 3, 0, m20));

    // Right column  (note: e24's middle c-candidate uses Cp(3,1,2)=cv[2][2] — faithful to source)
    const float e14 = sel2(E2 * MV(ev, 1, 4, m02), E5 * MV(ev, 1, 4, m12),
                           C2 * MV(cv, 1, 4, m02), C5 * MV(cv, 1, 4, m12));
    const float e24 = sel3(E2 * MV(ev, 2, 4, m02), E5 * MV(ev, 2, 4, m12), E8 * MV(ev, 2, 4, m22),
                           C2 * MV(cv, 2, 4, m02), C5 * MV(cv, 2, 2, m12), C8 * MV(cv, 2, 4, m22));
    const float e34 = sel2(E5 * MV(ev, 3, 4, m12), E8 * MV(ev, 3, 4, m22),
                           C5 * MV(cv, 3, 4, m12), C8 * MV(cv, 3, 4, m22));

    // Top row
    const float e01 = sel2(E0 * MV(ev, 0, 1, m00), E1 * MV(ev, 0, 1, m01),
                           C0 * MV(cv, 0, 1, m00), C1 * MV(cv, 0, 1, m01));
    const float e02 = sel3(E0 * MV(ev, 0, 2, m00), E1 * MV(ev, 0, 2, m01), E2 * MV(ev, 0, 2, m02),
                           C0 * MV(cv, 0, 2, m00), C1 * MV(cv, 0, 2, m01), C2 * MV(cv, 0, 2, m02));
    const float e03 = sel2(E1 * MV(ev, 0, 3, m01), E2 * MV(ev, 0, 3, m02),
                           C1 * MV(cv, 0, 3, m01), C2 * MV(cv, 0, 3, m02));

    // Bottom row
    const float e41 = sel2(E6 * MV(ev, 4, 1, m20), E7 * MV(ev, 4, 1, m21),
                           C6 * MV(cv, 4, 1, m20), C7 * MV(cv, 4, 1, m21));
    const float e42 = sel3(E6 * MV(ev, 4, 2, m20), E7 * MV(ev, 4, 2, m21), E8 * MV(ev, 4, 2, m22),
                           C6 * MV(cv, 4, 2, m20), C7 * MV(cv, 4, 2, m21), C8 * MV(cv, 4, 2, m22));
    const float e43 = sel2(E7 * MV(ev, 4, 3, m21), E8 * MV(ev, 4, 3, m22),
                           C7 * MV(cv, 4, 3, m21), C8 * MV(cv, 4, 3, m22));

#undef MV

    float o[25];
    o[0]  = e00; o[1]  = e01; o[2]  = e02; o[3]  = e03; o[4]  = e04;
    o[5]  = e10; o[6]  = E0;  o[7]  = E1;  o[8]  = E2;  o[9]  = e14;
    o[10] = e20; o[11] = E3;  o[12] = 1.f; o[13] = E5;  o[14] = e24;
    o[15] = e30; o[16] = E6;  o[17] = E7;  o[18] = E8;  o[19] = e34;
    o[20] = e40; o[21] = e41; o[22] = e42; o[23] = e43; o[24] = e44;

    float* __restrict__ obase = out + (size_t)bc * 25 * HWSZ + (size_t)y * BW + x;
#pragma unroll
    for (int k = 0; k < 25; ++k) {
        obase[(size_t)k * HWSZ] = o[k];
    }
}

extern "C" void kernel_launch(void* const* d_in, const int* in_sizes, int n_in,
                              void* d_out, int out_size, void* d_ws, size_t ws_size,
                              hipStream_t stream) {
    const float* e  = (const float*)d_in[0];
    const float* ce = (const float*)d_in[1];
    float* out = (float*)d_out;

    dim3 grid(BW / 64, BH / 4, BCN);   // (8, 64, 16)
    dim3 block(256);
    eprod25_kernel<<<grid, block, 0, stream>>>(e, ce, out);
}